// Round 1
// baseline (901.742 us; speedup 1.0000x reference)
//
#include <hip/hip_runtime.h>

#define D 128

// agg = (1 + eps) * x, vectorized float4
__global__ void k_init(const float* __restrict__ x, const float* __restrict__ eps,
                       float* __restrict__ agg, int total4) {
    int i = blockIdx.x * blockDim.x + threadIdx.x;
    if (i >= total4) return;
    float s = 1.0f + eps[0];
    float4 v = ((const float4*)x)[i];
    v.x *= s; v.y *= s; v.z *= s; v.w *= s;
    ((float4*)agg)[i] = v;
}

// one wave (64 lanes) per edge, each lane handles 2 consecutive features
__global__ void k_scatter(const float* __restrict__ x, const float* __restrict__ vals,
                          const int* __restrict__ rows, const int* __restrict__ cols,
                          float* __restrict__ agg, int E) {
    int e = blockIdx.x * 4 + (threadIdx.x >> 6);
    int l = threadIdx.x & 63;
    if (e >= E) return;
    int r = rows[e];
    int c = cols[e];
    float v = vals[e];
    float2 xv = *(const float2*)&x[(size_t)c * D + l * 2];
    atomicAdd(&agg[(size_t)r * D + l * 2 + 0], v * xv.x);
    atomicAdd(&agg[(size_t)r * D + l * 2 + 1], v * xv.y);
}

// out[N,128] = in[N,128] @ W[128,128] + bias, plus per-column sum / sumsq into stats[0..127]/[128..255]
// Block: 256 threads, 32 rows per block, thread computes 4 rows x 4 cols.
__global__ __launch_bounds__(256, 2)
void k_gemm_stats(const float* __restrict__ in, const float* __restrict__ W,
                  const float* __restrict__ bias, float* __restrict__ out,
                  float* __restrict__ stats, int N) {
    __shared__ float sW[D * D];      // 64 KB
    __shared__ float sIn[32 * D];    // 16 KB
    int tid = threadIdx.x;

    // load W (4096 float4)
    for (int v = tid; v < D * D / 4; v += 256)
        ((float4*)sW)[v] = ((const float4*)W)[v];

    int row0 = blockIdx.x * 32;
    // load 32-row input tile (1024 float4), zero-pad past N
    for (int v = tid; v < 32 * D / 4; v += 256) {
        int r = v >> 5;          // 32 float4 per row
        int gr = row0 + r;
        float4 val;
        if (gr < N) val = ((const float4*)in)[(size_t)gr * (D / 4) + (v & 31)];
        else        val = make_float4(0.f, 0.f, 0.f, 0.f);
        ((float4*)sIn)[v] = val;
    }
    __syncthreads();

    int j0 = (tid & 31) * 4;   // column group
    int r0 = (tid >> 5) * 4;   // row group

    float4 bv = *(const float4*)&bias[j0];
    float4 acc[4];
#pragma unroll
    for (int r = 0; r < 4; ++r) acc[r] = bv;

#pragma unroll 4
    for (int k = 0; k < D; ++k) {
        float4 w = *(const float4*)&sW[k * D + j0];
#pragma unroll
        for (int r = 0; r < 4; ++r) {
            float a = sIn[(r0 + r) * D + k];
            acc[r].x += a * w.x;
            acc[r].y += a * w.y;
            acc[r].z += a * w.z;
            acc[r].w += a * w.w;
        }
    }

    // write out + accumulate per-column partials
    float4 s = make_float4(0.f, 0.f, 0.f, 0.f);
    float4 q = make_float4(0.f, 0.f, 0.f, 0.f);
#pragma unroll
    for (int r = 0; r < 4; ++r) {
        int gr = row0 + r0 + r;
        if (gr < N) {
            *(float4*)&out[(size_t)gr * D + j0] = acc[r];
            s.x += acc[r].x; s.y += acc[r].y; s.z += acc[r].z; s.w += acc[r].w;
            q.x += acc[r].x * acc[r].x; q.y += acc[r].y * acc[r].y;
            q.z += acc[r].z * acc[r].z; q.w += acc[r].w * acc[r].w;
        }
    }

    // block-level column reduction across 8 row-groups (reuse sIn)
    __syncthreads();
    float* redS = sIn;            // 8*128 floats
    float* redQ = sIn + 8 * D;    // 8*128 floats
    *(float4*)&redS[(tid >> 5) * D + j0] = s;
    *(float4*)&redQ[(tid >> 5) * D + j0] = q;
    __syncthreads();
    if (tid < D) {
        float ts = 0.f, tq = 0.f;
#pragma unroll
        for (int g = 0; g < 8; ++g) {
            ts += redS[g * D + tid];
            tq += redQ[g * D + tid];
        }
        atomicAdd(&stats[tid], ts);
        atomicAdd(&stats[D + tid], tq);
    }
}

// turn (sum, sumsq) into fused (scale, shift): a = g*rsqrt(var+eps), b = be - mean*a
__global__ void k_stats(float* __restrict__ stats, const float* __restrict__ g,
                        const float* __restrict__ be, float invN) {
    int j = threadIdx.x;
    float mean = stats[j] * invN;
    float var = stats[D + j] * invN - mean * mean;
    var = fmaxf(var, 0.f);
    float inv = rsqrtf(var + 1e-5f);
    float a = g[j] * inv;
    float b = be[j] - mean * a;
    stats[j] = a;
    stats[D + j] = b;
}

// out = swish(in * a[col] + b[col]), float4
__global__ void k_bnswish(const float* __restrict__ in, float* __restrict__ out,
                          const float* __restrict__ stats, int total4) {
    __shared__ float sa[D], sb[D];
    if (threadIdx.x < D) {
        sa[threadIdx.x] = stats[threadIdx.x];
        sb[threadIdx.x] = stats[D + threadIdx.x];
    }
    __syncthreads();
    int i = blockIdx.x * blockDim.x + threadIdx.x;
    if (i >= total4) return;
    int j0 = (i * 4) & (D - 1);
    float4 v = ((const float4*)in)[i];
    float d0 = v.x * sa[j0 + 0] + sb[j0 + 0];
    float d1 = v.y * sa[j0 + 1] + sb[j0 + 1];
    float d2 = v.z * sa[j0 + 2] + sb[j0 + 2];
    float d3 = v.w * sa[j0 + 3] + sb[j0 + 3];
    float4 o;
    o.x = d0 / (1.0f + __expf(-d0));
    o.y = d1 / (1.0f + __expf(-d1));
    o.z = d2 / (1.0f + __expf(-d2));
    o.w = d3 / (1.0f + __expf(-d3));
    ((float4*)out)[i] = o;
}

extern "C" void kernel_launch(void* const* d_in, const int* in_sizes, int n_in,
                              void* d_out, int out_size, void* d_ws, size_t ws_size,
                              hipStream_t stream) {
    const float* x    = (const float*)d_in[0];
    const float* vals = (const float*)d_in[1];
    const float* W1   = (const float*)d_in[2];
    const float* b1   = (const float*)d_in[3];
    const float* g1   = (const float*)d_in[4];
    const float* be1  = (const float*)d_in[5];
    const float* W2   = (const float*)d_in[6];
    const float* b2   = (const float*)d_in[7];
    const float* g2   = (const float*)d_in[8];
    const float* be2  = (const float*)d_in[9];
    const float* eps  = (const float*)d_in[10];
    const int*  rows  = (const int*)d_in[11];
    const int*  cols  = (const int*)d_in[12];
    float* out = (float*)d_out;

    int N = in_sizes[0] / D;
    int E = in_sizes[1];

    float* agg   = (float*)d_ws;                 // N*D floats
    float* stats = agg + (size_t)N * D;          // 2*D floats

    int total4 = N * D / 4;
    int eb = (total4 + 255) / 256;
    int gblocks = (N + 31) / 32;
    float invN = 1.0f / (float)N;

    // agg = (1+eps)*x ; scatter-add edges
    k_init<<<eb, 256, 0, stream>>>(x, eps, agg, total4);
    k_scatter<<<(E + 3) / 4, 256, 0, stream>>>(x, vals, rows, cols, agg, E);

    // layer 1: GEMM+stats -> finalize -> BN+swish (in-place on out)
    hipMemsetAsync(stats, 0, 2 * D * sizeof(float), stream);
    k_gemm_stats<<<gblocks, 256, 0, stream>>>(agg, W1, b1, out, stats, N);
    k_stats<<<1, D, 0, stream>>>(stats, g1, be1, invN);
    k_bnswish<<<eb, 256, 0, stream>>>(out, out, stats, total4);

    // layer 2: GEMM+stats (out -> agg) -> finalize -> BN+swish (agg -> out)
    hipMemsetAsync(stats, 0, 2 * D * sizeof(float), stream);
    k_gemm_stats<<<gblocks, 256, 0, stream>>>(out, W2, b2, agg, stats, N);
    k_stats<<<1, D, 0, stream>>>(stats, g2, be2, invN);
    k_bnswish<<<eb, 256, 0, stream>>>(agg, out, stats, total4);
}

// Round 2
// 451.986 us; speedup vs baseline: 1.9951x; 1.9951x over previous
//
#include <hip/hip_runtime.h>

#define D 128

// ---- phase A: histogram of edge rows ----
__global__ void k_hist(const int* __restrict__ rows, int* __restrict__ cnt, int E) {
    int e = blockIdx.x * blockDim.x + threadIdx.x;
    if (e < E) atomicAdd(&cnt[rows[e]], 1);
}

// ---- phase B: exclusive prefix scan of cnt[0..n) -> off[0..n], single block 1024 thr ----
__global__ void k_scan(const int* __restrict__ cnt, int* __restrict__ off, int n) {
    __shared__ int wsum[16];
    __shared__ int carry_s;
    int tid = threadIdx.x;
    int lane = tid & 63, wid = tid >> 6;
    if (tid == 0) carry_s = 0;
    __syncthreads();
    for (int base = 0; base < n; base += 1024) {
        int i = base + tid;
        int v = (i < n) ? cnt[i] : 0;
        // inclusive scan within wave
        int s = v;
#pragma unroll
        for (int d = 1; d < 64; d <<= 1) {
            int t = __shfl_up(s, d, 64);
            if (lane >= d) s += t;
        }
        if (lane == 63) wsum[wid] = s;
        __syncthreads();
        if (wid == 0) {
            int ws = (lane < 16) ? wsum[lane] : 0;
            int ss = ws;
#pragma unroll
            for (int d = 1; d < 16; d <<= 1) {
                int t = __shfl_up(ss, d, 64);
                if (lane >= d) ss += t;
            }
            if (lane < 16) wsum[lane] = ss - ws;   // exclusive wave prefix
        }
        __syncthreads();
        int excl = (s - v) + wsum[wid] + carry_s;
        if (i < n) off[i] = excl;
        __syncthreads();                 // everyone has read carry_s
        if (tid == 1023) carry_s = excl + v;
        __syncthreads();                 // new carry visible
    }
    if (tid == 0) off[n] = carry_s;
}

// ---- phase C: bucket edges into CSR order: sedge[p] = (col, val) ----
__global__ void k_bucket(const int* __restrict__ rows, const int* __restrict__ cols,
                         const float* __restrict__ vals, const int* __restrict__ off,
                         int* __restrict__ cur, int2* __restrict__ sedge, int E) {
    int e = blockIdx.x * blockDim.x + threadIdx.x;
    if (e >= E) return;
    int r = rows[e];
    int p = off[r] + atomicAdd(&cur[r], 1);
    sedge[p] = make_int2(cols[e], __float_as_int(vals[e]));
}

// ---- phase D: segment-sum gather. one wave per node, lane owns 2 features.
//      agg[node] = (1+eps)*x[node] + sum_e val_e * x[col_e]
__global__ __launch_bounds__(256)
void k_gather(const float* __restrict__ x, const float* __restrict__ eps,
              const int* __restrict__ off, const int2* __restrict__ sedge,
              float* __restrict__ agg, int N) {
    int node = blockIdx.x * 4 + (threadIdx.x >> 6);
    int lane = threadIdx.x & 63;
    if (node >= N) return;
    float s = 1.0f + eps[0];
    size_t xi = (size_t)node * D + lane * 2;
    float2 a = *(const float2*)&x[xi];
    a.x *= s; a.y *= s;
    int b = off[node], e2 = off[node + 1];
    for (int i = b; i < e2; ++i) {
        int2 ed = sedge[i];
        float v = __int_as_float(ed.y);
        float2 xv = *(const float2*)&x[(size_t)ed.x * D + lane * 2];
        a.x += v * xv.x;
        a.y += v * xv.y;
    }
    *(float2*)&agg[xi] = a;
}

// ---- GEMM + batch stats (unchanged from round 1) ----
__global__ __launch_bounds__(256, 2)
void k_gemm_stats(const float* __restrict__ in, const float* __restrict__ W,
                  const float* __restrict__ bias, float* __restrict__ out,
                  float* __restrict__ stats, int N) {
    __shared__ float sW[D * D];      // 64 KB
    __shared__ float sIn[32 * D];    // 16 KB
    int tid = threadIdx.x;

    for (int v = tid; v < D * D / 4; v += 256)
        ((float4*)sW)[v] = ((const float4*)W)[v];

    int row0 = blockIdx.x * 32;
    for (int v = tid; v < 32 * D / 4; v += 256) {
        int r = v >> 5;
        int gr = row0 + r;
        float4 val;
        if (gr < N) val = ((const float4*)in)[(size_t)gr * (D / 4) + (v & 31)];
        else        val = make_float4(0.f, 0.f, 0.f, 0.f);
        ((float4*)sIn)[v] = val;
    }
    __syncthreads();

    int j0 = (tid & 31) * 4;
    int r0 = (tid >> 5) * 4;

    float4 bv = *(const float4*)&bias[j0];
    float4 acc[4];
#pragma unroll
    for (int r = 0; r < 4; ++r) acc[r] = bv;

#pragma unroll 4
    for (int k = 0; k < D; ++k) {
        float4 w = *(const float4*)&sW[k * D + j0];
#pragma unroll
        for (int r = 0; r < 4; ++r) {
            float a = sIn[(r0 + r) * D + k];
            acc[r].x += a * w.x;
            acc[r].y += a * w.y;
            acc[r].z += a * w.z;
            acc[r].w += a * w.w;
        }
    }

    float4 s = make_float4(0.f, 0.f, 0.f, 0.f);
    float4 q = make_float4(0.f, 0.f, 0.f, 0.f);
#pragma unroll
    for (int r = 0; r < 4; ++r) {
        int gr = row0 + r0 + r;
        if (gr < N) {
            *(float4*)&out[(size_t)gr * D + j0] = acc[r];
            s.x += acc[r].x; s.y += acc[r].y; s.z += acc[r].z; s.w += acc[r].w;
            q.x += acc[r].x * acc[r].x; q.y += acc[r].y * acc[r].y;
            q.z += acc[r].z * acc[r].z; q.w += acc[r].w * acc[r].w;
        }
    }

    __syncthreads();
    float* redS = sIn;
    float* redQ = sIn + 8 * D;
    *(float4*)&redS[(tid >> 5) * D + j0] = s;
    *(float4*)&redQ[(tid >> 5) * D + j0] = q;
    __syncthreads();
    if (tid < D) {
        float ts = 0.f, tq = 0.f;
#pragma unroll
        for (int g = 0; g < 8; ++g) {
            ts += redS[g * D + tid];
            tq += redQ[g * D + tid];
        }
        atomicAdd(&stats[tid], ts);
        atomicAdd(&stats[D + tid], tq);
    }
}

__global__ void k_stats(float* __restrict__ stats, const float* __restrict__ g,
                        const float* __restrict__ be, float invN) {
    int j = threadIdx.x;
    float mean = stats[j] * invN;
    float var = stats[D + j] * invN - mean * mean;
    var = fmaxf(var, 0.f);
    float inv = rsqrtf(var + 1e-5f);
    float a = g[j] * inv;
    float b = be[j] - mean * a;
    stats[j] = a;
    stats[D + j] = b;
}

__global__ void k_bnswish(const float* __restrict__ in, float* __restrict__ out,
                          const float* __restrict__ stats, int total4) {
    __shared__ float sa[D], sb[D];
    if (threadIdx.x < D) {
        sa[threadIdx.x] = stats[threadIdx.x];
        sb[threadIdx.x] = stats[D + threadIdx.x];
    }
    __syncthreads();
    int i = blockIdx.x * blockDim.x + threadIdx.x;
    if (i >= total4) return;
    int j0 = (i * 4) & (D - 1);
    float4 v = ((const float4*)in)[i];
    float d0 = v.x * sa[j0 + 0] + sb[j0 + 0];
    float d1 = v.y * sa[j0 + 1] + sb[j0 + 1];
    float d2 = v.z * sa[j0 + 2] + sb[j0 + 2];
    float d3 = v.w * sa[j0 + 3] + sb[j0 + 3];
    float4 o;
    o.x = d0 / (1.0f + __expf(-d0));
    o.y = d1 / (1.0f + __expf(-d1));
    o.z = d2 / (1.0f + __expf(-d2));
    o.w = d3 / (1.0f + __expf(-d3));
    ((float4*)out)[i] = o;
}

extern "C" void kernel_launch(void* const* d_in, const int* in_sizes, int n_in,
                              void* d_out, int out_size, void* d_ws, size_t ws_size,
                              hipStream_t stream) {
    const float* x    = (const float*)d_in[0];
    const float* vals = (const float*)d_in[1];
    const float* W1   = (const float*)d_in[2];
    const float* b1   = (const float*)d_in[3];
    const float* g1   = (const float*)d_in[4];
    const float* be1  = (const float*)d_in[5];
    const float* W2   = (const float*)d_in[6];
    const float* b2   = (const float*)d_in[7];
    const float* g2   = (const float*)d_in[8];
    const float* be2  = (const float*)d_in[9];
    const float* eps  = (const float*)d_in[10];
    const int*  rows  = (const int*)d_in[11];
    const int*  cols  = (const int*)d_in[12];
    float* out = (float*)d_out;

    int N = in_sizes[0] / D;
    int E = in_sizes[1];

    // workspace layout (keep 8B alignment for sedge)
    float* agg   = (float*)d_ws;                       // N*D floats
    float* stats = agg + (size_t)N * D;                // 2*D floats
    int*   cnt   = (int*)(stats + 2 * D);              // N ints
    int*   off   = cnt + N;                            // N+1 ints (pad to N+2)
    int2*  sedge = (int2*)(off + N + 2);               // E int2

    int total4 = N * D / 4;
    int eb = (total4 + 255) / 256;
    int gblocks = (N + 31) / 32;
    float invN = 1.0f / (float)N;

    // ---- build CSR by row ----
    hipMemsetAsync(cnt, 0, (size_t)N * sizeof(int), stream);
    k_hist<<<(E + 255) / 256, 256, 0, stream>>>(rows, cnt, E);
    k_scan<<<1, 1024, 0, stream>>>(cnt, off, N);
    hipMemsetAsync(cnt, 0, (size_t)N * sizeof(int), stream);
    k_bucket<<<(E + 255) / 256, 256, 0, stream>>>(rows, cols, vals, off, cnt, sedge, E);

    // ---- segment-sum gather (fused (1+eps)*x) ----
    k_gather<<<(N + 3) / 4, 256, 0, stream>>>(x, eps, off, sedge, agg, N);

    // ---- layer 1 ----
    hipMemsetAsync(stats, 0, 2 * D * sizeof(float), stream);
    k_gemm_stats<<<gblocks, 256, 0, stream>>>(agg, W1, b1, out, stats, N);
    k_stats<<<1, D, 0, stream>>>(stats, g1, be1, invN);
    k_bnswish<<<eb, 256, 0, stream>>>(out, out, stats, total4);

    // ---- layer 2 ----
    hipMemsetAsync(stats, 0, 2 * D * sizeof(float), stream);
    k_gemm_stats<<<gblocks, 256, 0, stream>>>(out, W2, b2, agg, stats, N);
    k_stats<<<1, D, 0, stream>>>(stats, g2, be2, invN);
    k_bnswish<<<eb, 256, 0, stream>>>(agg, out, stats, total4);
}

// Round 3
// 327.371 us; speedup vs baseline: 2.7545x; 1.3807x over previous
//
#include <hip/hip_runtime.h>

#define D 128
#define DH 64   // uints per feature row (2 bf16 per uint)

typedef float f32x4 __attribute__((ext_vector_type(4)));
typedef short s16x8 __attribute__((ext_vector_type(8)));

static __device__ __forceinline__ unsigned short f2bf(float f) {
    unsigned u = __float_as_uint(f);
    u += 0x7FFF + ((u >> 16) & 1);   // RNE
    return (unsigned short)(u >> 16);
}
static __device__ __forceinline__ float bflo(unsigned u) { return __uint_as_float(u << 16); }
static __device__ __forceinline__ float bfhi(unsigned u) { return __uint_as_float(u & 0xFFFF0000u); }

// ---- convert x (fp32) -> packed bf16 ----
__global__ void k_xbf16(const float* __restrict__ x, unsigned* __restrict__ xh, int total4) {
    int i = blockIdx.x * blockDim.x + threadIdx.x;
    if (i >= total4) return;
    float4 v = ((const float4*)x)[i];
    uint2 o;
    o.x = (unsigned)f2bf(v.x) | ((unsigned)f2bf(v.y) << 16);
    o.y = (unsigned)f2bf(v.z) | ((unsigned)f2bf(v.w) << 16);
    ((uint2*)xh)[i] = o;
}

// ---- histogram of edge rows ----
__global__ void k_hist(const int* __restrict__ rows, int* __restrict__ cnt, int E) {
    int e = blockIdx.x * blockDim.x + threadIdx.x;
    if (e < E) atomicAdd(&cnt[rows[e]], 1);
}

// ---- scan phase 1: per-1024-chunk exclusive scan + chunk totals ----
__global__ __launch_bounds__(1024)
void k_scan1(const int* __restrict__ cnt, int* __restrict__ off, int* __restrict__ csum, int n) {
    __shared__ int wsum[16];
    int tid = threadIdx.x, lane = tid & 63, wid = tid >> 6;
    int i = blockIdx.x * 1024 + tid;
    int v = (i < n) ? cnt[i] : 0;
    int s = v;
#pragma unroll
    for (int d = 1; d < 64; d <<= 1) { int t = __shfl_up(s, d, 64); if (lane >= d) s += t; }
    if (lane == 63) wsum[wid] = s;
    __syncthreads();
    if (wid == 0) {
        int ws = (lane < 16) ? wsum[lane] : 0;
        int ss = ws;
#pragma unroll
        for (int d = 1; d < 16; d <<= 1) { int t = __shfl_up(ss, d, 64); if (lane >= d) ss += t; }
        if (lane < 16) wsum[lane] = ss - ws;
    }
    __syncthreads();
    int excl = (s - v) + wsum[wid];
    if (i < n) off[i] = excl;
    if (tid == 1023) csum[blockIdx.x] = excl + v;
}

// ---- scan phase 2: exclusive scan of <=64 chunk totals (one wave) ----
__global__ void k_scan2(int* __restrict__ csum, int* __restrict__ off, int n, int nc) {
    int lane = threadIdx.x;
    int v = (lane < nc) ? csum[lane] : 0;
    int s = v;
#pragma unroll
    for (int d = 1; d < 64; d <<= 1) { int t = __shfl_up(s, d, 64); if (lane >= d) s += t; }
    if (lane < nc) csum[lane] = s - v;
    if (lane == 63) off[n] = s;   // grand total
}

// ---- scan phase 3: add chunk bases ----
__global__ __launch_bounds__(1024)
void k_scan3(int* __restrict__ off, const int* __restrict__ csum, int n) {
    int i = blockIdx.x * 1024 + threadIdx.x;
    if (i < n) off[i] += csum[blockIdx.x];
}

// ---- bucket edges into CSR order ----
__global__ void k_bucket(const int* __restrict__ rows, const int* __restrict__ cols,
                         const float* __restrict__ vals, const int* __restrict__ off,
                         int* __restrict__ cur, int2* __restrict__ sedge, int E) {
    int e = blockIdx.x * blockDim.x + threadIdx.x;
    if (e >= E) return;
    int r = rows[e];
    int p = off[r] + atomicAdd(&cur[r], 1);
    sedge[p] = make_int2(cols[e], __float_as_int(vals[e]));
}

// ---- segment-sum gather (bf16 rows, fp32 accumulate, x4 unroll) ----
__global__ __launch_bounds__(256)
void k_gather(const unsigned* __restrict__ xh, const float* __restrict__ eps,
              const int* __restrict__ off, const int2* __restrict__ sedge,
              unsigned* __restrict__ aggh, int N) {
    int node = blockIdx.x * 4 + (threadIdx.x >> 6);
    int lane = threadIdx.x & 63;
    if (node >= N) return;
    float s = 1.0f + eps[0];
    unsigned u = xh[(size_t)node * DH + lane];
    float ax = s * bflo(u), ay = s * bfhi(u);
    int b = off[node], e = off[node + 1];
    int i = b;
    for (; i + 4 <= e; i += 4) {
        int2 e0 = sedge[i], e1 = sedge[i + 1], e2 = sedge[i + 2], e3 = sedge[i + 3];
        unsigned u0 = xh[(size_t)e0.x * DH + lane];
        unsigned u1 = xh[(size_t)e1.x * DH + lane];
        unsigned u2 = xh[(size_t)e2.x * DH + lane];
        unsigned u3 = xh[(size_t)e3.x * DH + lane];
        float v0 = __int_as_float(e0.y), v1 = __int_as_float(e1.y);
        float v2 = __int_as_float(e2.y), v3 = __int_as_float(e3.y);
        ax += v0 * bflo(u0) + v1 * bflo(u1) + v2 * bflo(u2) + v3 * bflo(u3);
        ay += v0 * bfhi(u0) + v1 * bfhi(u1) + v2 * bfhi(u2) + v3 * bfhi(u3);
    }
    for (; i < e; ++i) {
        int2 ed = sedge[i];
        unsigned uu = xh[(size_t)ed.x * DH + lane];
        float v = __int_as_float(ed.y);
        ax += v * bflo(uu);
        ay += v * bfhi(uu);
    }
    aggh[(size_t)node * DH + lane] = (unsigned)f2bf(ax) | ((unsigned)f2bf(ay) << 16);
}

// ---- pre-swizzle W (fp32 128x128) into 16x16x32 MFMA B-fragment layout, bf16 ----
// Wsw[((kt*8+nt)*64+lane)*8+j] = bf16( W[kt*32 + (lane>>4)*8 + j][nt*16 + (lane&15)] )
__global__ void k_prepw(const float* __restrict__ W, unsigned short* __restrict__ Wsw) {
    int idx = blockIdx.x * 256 + threadIdx.x;   // 0..2047
    if (idx >= 2048) return;
    int lane = idx & 63, nt = (idx >> 6) & 7, kt = idx >> 9;
    int k0 = kt * 32 + (lane >> 4) * 8;
    int n = nt * 16 + (lane & 15);
    unsigned short* dst = &Wsw[(size_t)((kt * 8 + nt) * 64 + lane) * 8];
#pragma unroll
    for (int j = 0; j < 8; ++j) dst[j] = f2bf(W[(k0 + j) * D + n]);
}

// ---- MFMA GEMM: H[N,128] = A[N,128](bf16) @ W + bias, fused batch-stat partials ----
// block = 256 thr = 4 waves; wave w owns rows [blk*64 + w*16, +16), all 128 cols.
__global__ __launch_bounds__(256)
void k_gemm(const unsigned short* __restrict__ A, const unsigned short* __restrict__ Wsw,
            const float* __restrict__ bias, unsigned short* __restrict__ Hout,
            float* __restrict__ stats, int N) {
    __shared__ float redS[4 * D];
    __shared__ float redQ[4 * D];
    int tid = threadIdx.x, lane = tid & 63, w = tid >> 6;
    int row0 = blockIdx.x * 64 + w * 16;
    int m = lane & 15, quad = lane >> 4;

    f32x4 acc[8];
#pragma unroll
    for (int nt = 0; nt < 8; ++nt) acc[nt] = (f32x4){0.f, 0.f, 0.f, 0.f};

    int arow = row0 + m;
    bool avalid = arow < N;
    const s16x8* wp = (const s16x8*)Wsw;
    s16x8 az = {0, 0, 0, 0, 0, 0, 0, 0};
#pragma unroll
    for (int kt = 0; kt < 4; ++kt) {
        s16x8 a = avalid ? *(const s16x8*)&A[(size_t)arow * D + kt * 32 + quad * 8] : az;
#pragma unroll
        for (int nt = 0; nt < 8; ++nt) {
            s16x8 b = wp[(kt * 8 + nt) * 64 + lane];
            acc[nt] = __builtin_amdgcn_mfma_f32_16x16x32_bf16(a, b, acc[nt], 0, 0, 0);
        }
    }

#pragma unroll
    for (int nt = 0; nt < 8; ++nt) {
        float bv = bias[nt * 16 + m];
        float s = 0.f, q = 0.f;
#pragma unroll
        for (int r = 0; r < 4; ++r) {
            int row = row0 + quad * 4 + r;
            float h = acc[nt][r] + bv;
            if (row < N) {
                Hout[(size_t)row * D + nt * 16 + m] = f2bf(h);
                s += h; q += h * h;
            }
        }
        s += __shfl_xor(s, 16, 64); s += __shfl_xor(s, 32, 64);
        q += __shfl_xor(q, 16, 64); q += __shfl_xor(q, 32, 64);
        if (quad == 0) {
            redS[w * D + nt * 16 + m] = s;
            redQ[w * D + nt * 16 + m] = q;
        }
    }
    __syncthreads();
    if (tid < D) {
        float ts = redS[tid] + redS[D + tid] + redS[2 * D + tid] + redS[3 * D + tid];
        float tq = redQ[tid] + redQ[D + tid] + redQ[2 * D + tid] + redQ[3 * D + tid];
        atomicAdd(&stats[tid], ts);
        atomicAdd(&stats[D + tid], tq);
    }
}

// ---- finalize: (sum,sumsq) -> fused (scale, shift) ----
__global__ void k_stats(float* __restrict__ stats, const float* __restrict__ g,
                        const float* __restrict__ be, float invN) {
    int j = threadIdx.x;
    float mean = stats[j] * invN;
    float var = stats[D + j] * invN - mean * mean;
    var = fmaxf(var, 0.f);
    float inv = rsqrtf(var + 1e-5f);
    float a = g[j] * inv;
    float b = be[j] - mean * a;
    stats[j] = a;
    stats[D + j] = b;
}

// ---- BN + swish on bf16 input; out bf16 (layer1) or fp32 (final) ----
template <bool F32OUT>
__global__ void k_bnswish(const unsigned* __restrict__ inh, void* __restrict__ outp,
                          const float* __restrict__ stats, int total4) {
    __shared__ float sa[D], sb[D];
    if (threadIdx.x < D) {
        sa[threadIdx.x] = stats[threadIdx.x];
        sb[threadIdx.x] = stats[D + threadIdx.x];
    }
    __syncthreads();
    int i = blockIdx.x * blockDim.x + threadIdx.x;
    if (i >= total4) return;
    uint2 u = ((const uint2*)inh)[i];
    int c = (i * 4) & (D - 1);
    float d0 = bflo(u.x) * sa[c + 0] + sb[c + 0];
    float d1 = bfhi(u.x) * sa[c + 1] + sb[c + 1];
    float d2 = bflo(u.y) * sa[c + 2] + sb[c + 2];
    float d3 = bfhi(u.y) * sa[c + 3] + sb[c + 3];
    float o0 = d0 / (1.f + __expf(-d0));
    float o1 = d1 / (1.f + __expf(-d1));
    float o2 = d2 / (1.f + __expf(-d2));
    float o3 = d3 / (1.f + __expf(-d3));
    if (F32OUT) {
        ((float4*)outp)[i] = make_float4(o0, o1, o2, o3);
    } else {
        uint2 o;
        o.x = (unsigned)f2bf(o0) | ((unsigned)f2bf(o1) << 16);
        o.y = (unsigned)f2bf(o2) | ((unsigned)f2bf(o3) << 16);
        ((uint2*)outp)[i] = o;
    }
}

extern "C" void kernel_launch(void* const* d_in, const int* in_sizes, int n_in,
                              void* d_out, int out_size, void* d_ws, size_t ws_size,
                              hipStream_t stream) {
    const float* x    = (const float*)d_in[0];
    const float* vals = (const float*)d_in[1];
    const float* W1   = (const float*)d_in[2];
    const float* b1   = (const float*)d_in[3];
    const float* g1   = (const float*)d_in[4];
    const float* be1  = (const float*)d_in[5];
    const float* W2   = (const float*)d_in[6];
    const float* b2   = (const float*)d_in[7];
    const float* g2   = (const float*)d_in[8];
    const float* be2  = (const float*)d_in[9];
    const float* eps  = (const float*)d_in[10];
    const int*  rows  = (const int*)d_in[11];
    const int*  cols  = (const int*)d_in[12];
    float* out = (float*)d_out;

    int N = in_sizes[0] / D;
    int E = in_sizes[1];

    // ---- workspace layout ----
    char* p = (char*)d_ws;
    float* stats = (float*)p;              p += 2 * D * sizeof(float);
    int* cnt = (int*)p;                    p += (size_t)N * sizeof(int);
    int* off = (int*)p;                    p += (size_t)(N + 2) * sizeof(int);
    int* csum = (int*)p;                   p += 64 * sizeof(int);
    p = (char*)(((uintptr_t)p + 15) & ~(uintptr_t)15);
    unsigned short* Wsw1 = (unsigned short*)p; p += (size_t)D * D * 2;
    unsigned short* Wsw2 = (unsigned short*)p; p += (size_t)D * D * 2;
    p = (char*)(((uintptr_t)p + 15) & ~(uintptr_t)15);
    int2* sedge = (int2*)p;                p += (size_t)E * sizeof(int2);
    unsigned* xh = (unsigned*)p;           p += (size_t)N * DH * sizeof(unsigned);  // also h-buffer
    unsigned* aggh = (unsigned*)p;         /* N*DH uints */

    int total4 = N * D / 4;                 // fp32-float4 / 4-elem groups
    int eb = (total4 + 255) / 256;
    int nc = (N + 1023) / 1024;             // scan chunks (<=64 for N<=65536)
    int gblk = (N + 63) / 64;
    float invN = 1.0f / (float)N;

    // ---- x -> bf16; W -> swizzled bf16 frags ----
    k_xbf16<<<eb, 256, 0, stream>>>(x, xh, total4);
    k_prepw<<<8, 256, 0, stream>>>(W1, Wsw1);
    k_prepw<<<8, 256, 0, stream>>>(W2, Wsw2);

    // ---- CSR build ----
    hipMemsetAsync(cnt, 0, (size_t)N * sizeof(int), stream);
    k_hist<<<(E + 255) / 256, 256, 0, stream>>>(rows, cnt, E);
    k_scan1<<<nc, 1024, 0, stream>>>(cnt, off, csum, N);
    k_scan2<<<1, 64, 0, stream>>>(csum, off, N, nc);
    k_scan3<<<nc, 1024, 0, stream>>>(off, csum, N);
    hipMemsetAsync(cnt, 0, (size_t)N * sizeof(int), stream);
    k_bucket<<<(E + 255) / 256, 256, 0, stream>>>(rows, cols, vals, off, cnt, sedge, E);

    // ---- gather (bf16) ----
    k_gather<<<(N + 3) / 4, 256, 0, stream>>>(xh, eps, off, sedge, aggh, N);

    // ---- layer 1: MFMA GEMM -> stats -> BN+swish (bf16 out into aggh) ----
    hipMemsetAsync(stats, 0, 2 * D * sizeof(float), stream);
    k_gemm<<<gblk, 256, 0, stream>>>((const unsigned short*)aggh, Wsw1, b1,
                                     (unsigned short*)xh, stats, N);
    k_stats<<<1, D, 0, stream>>>(stats, g1, be1, invN);
    k_bnswish<false><<<eb, 256, 0, stream>>>(xh, aggh, stats, total4);

    // ---- layer 2: MFMA GEMM -> stats -> BN+swish (fp32 out) ----
    hipMemsetAsync(stats, 0, 2 * D * sizeof(float), stream);
    k_gemm<<<gblk, 256, 0, stream>>>((const unsigned short*)aggh, Wsw2, b2,
                                     (unsigned short*)xh, stats, N);
    k_stats<<<1, D, 0, stream>>>(stats, g2, be2, invN);
    k_bnswish<true><<<eb, 256, 0, stream>>>(xh, out, stats, total4);
}